// Round 7
// baseline (241.678 us; speedup 1.0000x reference)
//
#include <hip/hip_runtime.h>
#include <math.h>

typedef float v4f __attribute__((ext_vector_type(4)));
typedef short bf16x8 __attribute__((ext_vector_type(8)));

#define AS1 __attribute__((address_space(1)))
#define AS3 __attribute__((address_space(3)))

static constexpr int Bn = 8192;   // batch
static constexpr int Hn = 768;    // hidden
static constexpr float invB = 1.0f / 8192.0f;

__device__ __forceinline__ short f32_to_bf16(float x) {
    union { float f; unsigned u; } v; v.f = x;
    unsigned r = (v.u + 0x7FFFu + ((v.u >> 16) & 1u)) >> 16;
    return (short)r;
}

// tanh(x) = 1 - 2/(exp(2x)+1)
__device__ __forceinline__ float fast_tanh(float x) {
    float xc = fminf(fmaxf(x, -15.0f), 15.0f);
    float e = __expf(2.0f * xc);
    float r = __builtin_amdgcn_rcpf(e + 1.0f);
    return 1.0f - 2.0f * r;
}

// XCD-aware swizzle: linear block id L -> (rowblock, colblock) such that
// XCD k (= L % 8) owns rowblocks {k, k+8, ..., k+56} x all 6 colblocks.
// Per-XCD working set: 8-rowblock A-slab (~3.1 MB) + W tile wave (~0.4 MB) < 4 MB L2.
__device__ __forceinline__ void swizzle_rc(int L, int& rb, int& cb) {
    const int k8 = L & 7, j = L >> 3;      // j in 0..47
    rb = k8 + 8 * (j & 7);                 // 0..63
    cb = j >> 3;                           // 0..5
}

// ---------------- fused prep: zero accumulators + fp32->bf16 all 5 tensors ----------------
__global__ void prep_kernel(const float* __restrict__ A,
                            const float* __restrict__ W1m, const float* __restrict__ W2m,
                            const float* __restrict__ W1v, const float* __restrict__ W2v,
                            short* __restrict__ A_bf,
                            short* __restrict__ W1m_bf, short* __restrict__ W2m_bf,
                            short* __restrict__ W1v_bf, short* __restrict__ W2v_bf,
                            float* __restrict__ zbuf, int nzero) {
    const int tid = blockIdx.x * blockDim.x + threadIdx.x;
    if (tid < nzero) zbuf[tid] = 0.0f;
    constexpr int A4 = Bn * Hn / 4;
    constexpr int W4 = Hn * Hn / 4;
    const int total = A4 + 4 * W4;
    const int stride = gridDim.x * blockDim.x;
    for (int i = tid; i < total; i += stride) {
        const float* s; short* d; int j;
        if (i < A4) { s = A; d = A_bf; j = i; }
        else {
            int k = i - A4; int w = k / W4; j = k - w * W4;
            s = (w == 0) ? W1m : (w == 1) ? W2m : (w == 2) ? W1v : W2v;
            d = (w == 0) ? W1m_bf : (w == 1) ? W2m_bf : (w == 2) ? W1v_bf : W2v_bf;
        }
        float4 v = ((const float4*)s)[j];
        short4 o;
        o.x = f32_to_bf16(v.x); o.y = f32_to_bf16(v.y);
        o.z = f32_to_bf16(v.z); o.w = f32_to_bf16(v.w);
        ((short4*)d)[j] = o;
    }
}

// ---------------- LAYER 1: branch-PAIRED 128x128 tile, XCD-swizzled ----------------
__launch_bounds__(256, 3)
__global__ void gemm_l1(const short* __restrict__ A_g,
                        const short* __restrict__ Wm_g, const short* __restrict__ Wv_g,
                        const float* __restrict__ bm, const float* __restrict__ bv,
                        short* __restrict__ outm, short* __restrict__ outv) {
    constexpr int K = Hn;
    __shared__ __align__(16) short smem[24576];   // 48KB: As 8192 | Wm 8192 | Wv 8192
    short* As = smem;
    short* Wms = smem + 8192;
    short* Wvs = smem + 16384;

    int rb, cb; swizzle_rc(blockIdx.x, rb, cb);
    const int row0 = rb * 128;
    const int col0 = cb * 128;

    const int t = threadIdx.x;
    const int w = t >> 6, lane = t & 63;
    const int wm = w >> 1, wn = w & 1;    // 2x2 waves, 64x64 wave-tile per branch
    const int lr = lane & 15, quad = lane >> 4;

    const int rt = t >> 3;                // 0..31
    const int bsrc = (t & 7) ^ (rt & 7);  // XOR-swizzled k-block source

    const short* pA[4]; const short* pWm[4]; const short* pWv[4];
#pragma unroll
    for (int i = 0; i < 4; ++i) {
        pA[i]  = A_g  + (size_t)(row0 + i * 32 + rt) * K + bsrc * 8;
        pWm[i] = Wm_g + (size_t)(col0 + i * 32 + rt) * K + bsrc * 8;
        pWv[i] = Wv_g + (size_t)(col0 + i * 32 + rt) * K + bsrc * 8;
    }

    v4f accm[4][4] = {}, accv[4][4] = {};

    for (int k0 = 0; k0 < K; k0 += 64) {
#pragma unroll
        for (int i = 0; i < 4; ++i) {
            __builtin_amdgcn_global_load_lds((AS1 void*)pA[i],  (AS3 void*)&As[i * 2048 + t * 8], 16, 0, 0);
            __builtin_amdgcn_global_load_lds((AS1 void*)pWm[i], (AS3 void*)&Wms[i * 2048 + t * 8], 16, 0, 0);
            __builtin_amdgcn_global_load_lds((AS1 void*)pWv[i], (AS3 void*)&Wvs[i * 2048 + t * 8], 16, 0, 0);
            pA[i] += 64; pWm[i] += 64; pWv[i] += 64;
        }
        __syncthreads();
#pragma unroll
        for (int s = 0; s < 2; ++s) {
            const int kb = s * 4 + quad;
            bf16x8 af[4], fm[4], fv[4];
#pragma unroll
            for (int mt = 0; mt < 4; ++mt) {
                int m = wm * 64 + mt * 16 + lr;
                af[mt] = *(const bf16x8*)&As[m * 64 + ((kb ^ (m & 7)) << 3)];
            }
#pragma unroll
            for (int nt = 0; nt < 4; ++nt) {
                int n = wn * 64 + nt * 16 + lr;
                int off = n * 64 + ((kb ^ (n & 7)) << 3);
                fm[nt] = *(const bf16x8*)&Wms[off];
                fv[nt] = *(const bf16x8*)&Wvs[off];
            }
#pragma unroll
            for (int mt = 0; mt < 4; ++mt)
#pragma unroll
                for (int nt = 0; nt < 4; ++nt) {
                    accm[mt][nt] = __builtin_amdgcn_mfma_f32_16x16x32_bf16(af[mt], fm[nt], accm[mt][nt], 0, 0, 0);
                    accv[mt][nt] = __builtin_amdgcn_mfma_f32_16x16x32_bf16(af[mt], fv[nt], accv[mt][nt], 0, 0, 0);
                }
        }
        __syncthreads();
    }

    // ---- epilogue: per branch, tanh -> LDS (128 x 136-padded) -> coalesced 16B stores ----
#pragma unroll
    for (int br = 0; br < 2; ++br) {
        const float* bias = br ? bv : bm;
        short* out = br ? outv : outm;
#pragma unroll
        for (int nt = 0; nt < 4; ++nt) {
            const int col_l = wn * 64 + nt * 16 + lr;
            const float bc = bias[col0 + col_l];
#pragma unroll
            for (int mt = 0; mt < 4; ++mt) {
#pragma unroll
                for (int r = 0; r < 4; ++r) {
                    const int row_l = wm * 64 + mt * 16 + quad * 4 + r;
                    float v = (br ? accv[mt][nt][r] : accm[mt][nt][r]) + bc;
                    smem[row_l * 136 + col_l] = f32_to_bf16(fast_tanh(v));
                }
            }
        }
        __syncthreads();
#pragma unroll
        for (int p = 0; p < 8; ++p) {
            const int c = p * 256 + t;
            const int row = c >> 4, rem = c & 15;
            bf16x8 v = *(const bf16x8*)&smem[row * 136 + rem * 8];
            *(bf16x8*)&out[(size_t)(row0 + row) * Hn + col0 + rem * 8] = v;
        }
        __syncthreads();
    }
}

// ---------------- LAYER 2: branch-paired 128x128 tile, XCD-swizzled, CLUB epilogue + finalize ----------------
__launch_bounds__(256, 2)
__global__ void gemm_l2(const short* __restrict__ Am_g, const short* __restrict__ Av_g,
                        const short* __restrict__ Wm_g, const short* __restrict__ Wv_g,
                        const float* __restrict__ bm, const float* __restrict__ bv,
                        const float* __restrict__ mb,
                        float* __restrict__ cs, float* __restrict__ cs2,
                        float* __restrict__ siv, float* __restrict__ sivmu,
                        float* __restrict__ accum, float* __restrict__ outp) {
    constexpr int K = Hn;
    __shared__ __align__(16) short smem[32768];   // 64KB
    short* Ams = smem;
    short* Avs = smem + 8192;
    short* Wms = smem + 16384;
    short* Wvs = smem + 24576;

    int rb, cb; swizzle_rc(blockIdx.x, rb, cb);
    const int row0 = rb * 128;
    const int col0 = cb * 128;

    const int t = threadIdx.x;
    const int w = t >> 6, lane = t & 63;
    const int wm = w >> 1, wn = w & 1;
    const int lr = lane & 15, quad = lane >> 4;

    const int rt = t >> 3;
    const int bsrc = (t & 7) ^ (rt & 7);

    const short* pAm[4]; const short* pAv[4]; const short* pWm[4]; const short* pWv[4];
#pragma unroll
    for (int i = 0; i < 4; ++i) {
        pAm[i] = Am_g + (size_t)(row0 + i * 32 + rt) * K + bsrc * 8;
        pAv[i] = Av_g + (size_t)(row0 + i * 32 + rt) * K + bsrc * 8;
        pWm[i] = Wm_g + (size_t)(col0 + i * 32 + rt) * K + bsrc * 8;
        pWv[i] = Wv_g + (size_t)(col0 + i * 32 + rt) * K + bsrc * 8;
    }

    v4f accm[4][4] = {}, accv[4][4] = {};

    for (int k0 = 0; k0 < K; k0 += 64) {
#pragma unroll
        for (int i = 0; i < 4; ++i) {
            __builtin_amdgcn_global_load_lds((AS1 void*)pAm[i], (AS3 void*)&Ams[i * 2048 + t * 8], 16, 0, 0);
            __builtin_amdgcn_global_load_lds((AS1 void*)pAv[i], (AS3 void*)&Avs[i * 2048 + t * 8], 16, 0, 0);
            __builtin_amdgcn_global_load_lds((AS1 void*)pWm[i], (AS3 void*)&Wms[i * 2048 + t * 8], 16, 0, 0);
            __builtin_amdgcn_global_load_lds((AS1 void*)pWv[i], (AS3 void*)&Wvs[i * 2048 + t * 8], 16, 0, 0);
            pAm[i] += 64; pAv[i] += 64; pWm[i] += 64; pWv[i] += 64;
        }
        __syncthreads();
#pragma unroll
        for (int s = 0; s < 2; ++s) {
            const int kb = s * 4 + quad;
            bf16x8 fam[4], fav[4], fwm[4], fwv[4];
#pragma unroll
            for (int mt = 0; mt < 4; ++mt) {
                int m = wm * 64 + mt * 16 + lr;
                int off = m * 64 + ((kb ^ (m & 7)) << 3);
                fam[mt] = *(const bf16x8*)&Ams[off];
                fav[mt] = *(const bf16x8*)&Avs[off];
            }
#pragma unroll
            for (int nt = 0; nt < 4; ++nt) {
                int n = wn * 64 + nt * 16 + lr;
                int off = n * 64 + ((kb ^ (n & 7)) << 3);
                fwm[nt] = *(const bf16x8*)&Wms[off];
                fwv[nt] = *(const bf16x8*)&Wvs[off];
            }
#pragma unroll
            for (int mt = 0; mt < 4; ++mt)
#pragma unroll
                for (int nt = 0; nt < 4; ++nt) {
                    accm[mt][nt] = __builtin_amdgcn_mfma_f32_16x16x32_bf16(fam[mt], fwm[nt], accm[mt][nt], 0, 0, 0);
                    accv[mt][nt] = __builtin_amdgcn_mfma_f32_16x16x32_bf16(fav[mt], fwv[nt], accv[mt][nt], 0, 0, 0);
                }
        }
        __syncthreads();
    }

    // ---------------- CLUB epilogue ----------------
    float pos = 0.f, q = 0.f;   // pos = sum iv*(mu-mb)^2 ; q = sum iv*mu^2
#pragma unroll
    for (int nt = 0; nt < 4; ++nt) {
        const int col = col0 + wn * 64 + nt * 16 + lr;
        const float bmc = bm[col], bvc = bv[col];
        float c1 = 0.f, c2 = 0.f, c3 = 0.f, c4 = 0.f;
#pragma unroll
        for (int mt = 0; mt < 4; ++mt) {
#pragma unroll
            for (int r = 0; r < 4; ++r) {
                const int row = row0 + wm * 64 + mt * 16 + quad * 4 + r;
                float mu = accm[mt][nt][r] + bmc;
                float tv = fast_tanh(accv[mt][nt][r] + bvc);
                float iv = __expf(-tv);
                float mbv = mb[(size_t)row * Hn + col];
                float d = mu - mbv;
                pos += iv * d * d;
                q   += iv * mu * mu;
                c1 += mu; c2 += mu * mu; c3 += iv; c4 += iv * mu;
            }
        }
        c1 += __shfl_xor(c1, 16); c1 += __shfl_xor(c1, 32);
        c2 += __shfl_xor(c2, 16); c2 += __shfl_xor(c2, 32);
        c3 += __shfl_xor(c3, 16); c3 += __shfl_xor(c3, 32);
        c4 += __shfl_xor(c4, 16); c4 += __shfl_xor(c4, 32);
        if (quad == 0) {
            atomicAdd(&cs[col], c1);
            atomicAdd(&cs2[col], c2);
            atomicAdd(&siv[col], c3);
            atomicAdd(&sivmu[col], c4);
        }
    }
    // block-reduce the two scalars
    for (int off = 32; off > 0; off >>= 1) {
        pos += __shfl_down(pos, off);
        q   += __shfl_down(q, off);
    }
    __shared__ float redP[4], redQ[4];
    if (lane == 0) { redP[w] = pos; redQ[w] = q; }
    __syncthreads();
    __shared__ int is_last;
    if (t == 0) {
        atomicAdd(&accum[0], redP[0] + redP[1] + redP[2] + redP[3]);
        atomicAdd(&accum[1], redQ[0] + redQ[1] + redQ[2] + redQ[3]);
        __threadfence();
        unsigned old = atomicAdd((unsigned int*)&accum[3], 1u);
        is_last = (old == gridDim.x - 1) ? 1 : 0;
    }
    __syncthreads();
    if (is_last) {
        float term = 0.f;
        for (int h = t; h < Hn; h += 256) {
            float v1 = atomicAdd(&cs[h], 0.0f);
            float v2 = atomicAdd(&cs2[h], 0.0f);
            float v3 = atomicAdd(&siv[h], 0.0f);
            float v4 = atomicAdd(&sivmu[h], 0.0f);
            term += v3 * v2 - 2.0f * v4 * v1;
        }
        for (int off = 32; off > 0; off >>= 1) term += __shfl_down(term, off);
        __shared__ float redT[4];
        if (lane == 0) redT[w] = term;
        __syncthreads();
        if (t == 0) {
            float T = redT[0] + redT[1] + redT[2] + redT[3];
            float P = atomicAdd(&accum[0], 0.0f);
            float Q = atomicAdd(&accum[1], 0.0f);
            float pos_sum = -0.5f * P;
            float neg_sum = -0.5f * (T * invB + Q);
            outp[0] = pos_sum * invB;
            outp[1] = (pos_sum - neg_sum) * invB;
        }
    }
}

extern "C" void kernel_launch(void* const* d_in, const int* in_sizes, int n_in,
                              void* d_out, int out_size, void* d_ws, size_t ws_size,
                              hipStream_t stream) {
    const float* modal_a = (const float*)d_in[0];
    const float* modal_b = (const float*)d_in[1];
    const float* W1m = (const float*)d_in[2];
    const float* b1m = (const float*)d_in[3];
    const float* W2m = (const float*)d_in[4];
    const float* b2m = (const float*)d_in[5];
    const float* W1v = (const float*)d_in[6];
    const float* b1v = (const float*)d_in[7];
    const float* W2v = (const float*)d_in[8];
    const float* b2v = (const float*)d_in[9];
    float* out = (float*)d_out;

    char* ws = (char*)d_ws;
    constexpr size_t szAH = (size_t)Bn * Hn * 2;   // bf16 [B,H]
    constexpr size_t szW  = (size_t)Hn * Hn * 2;   // bf16 [H,H]
    short* A_bf   = (short*)(ws);
    short* h1m    = (short*)(ws + szAH);
    short* h1v    = (short*)(ws + 2 * szAH);
    short* W1m_bf = (short*)(ws + 3 * szAH);
    short* W2m_bf = (short*)(ws + 3 * szAH + szW);
    short* W1v_bf = (short*)(ws + 3 * szAH + 2 * szW);
    short* W2v_bf = (short*)(ws + 3 * szAH + 3 * szW);
    float* cs     = (float*)(ws + 3 * szAH + 4 * szW);
    float* cs2    = cs + Hn;
    float* siv    = cs + 2 * Hn;
    float* sivmu  = cs + 3 * Hn;
    float* accum  = cs + 4 * Hn;   // [0]=P [1]=Q [2]=pad [3]=ticket

    // 1. fused zero + convert
    prep_kernel<<<1280, 256, 0, stream>>>(modal_a, W1m, W2m, W1v, W2v,
                                          A_bf, W1m_bf, W2m_bf, W1v_bf, W2v_bf,
                                          cs, 4 * Hn + 8);

    // 2. layer-1 paired GEMM, XCD-swizzled 1D grid (384 blocks)
    gemm_l1<<<384, 256, 0, stream>>>(
        A_bf, W1m_bf, W1v_bf, b1m, b1v, h1m, h1v);

    // 3. layer-2 paired GEMM, XCD-swizzled + CLUB epilogue + in-kernel finalize
    gemm_l2<<<384, 256, 0, stream>>>(
        h1m, h1v, W2m_bf, W2v_bf, b2m, b2v, modal_b,
        cs, cs2, siv, sivmu, accum, out);
}

// Round 8
// 176.879 us; speedup vs baseline: 1.3663x; 1.3663x over previous
//
#include <hip/hip_runtime.h>
#include <hip/hip_fp8.h>
#include <math.h>

typedef float v4f __attribute__((ext_vector_type(4)));

#define AS1 __attribute__((address_space(1)))
#define AS3 __attribute__((address_space(3)))

static constexpr int Bn = 8192;   // batch
static constexpr int Hn = 768;    // hidden
static constexpr float invB = 1.0f / 8192.0f;

__device__ __forceinline__ unsigned char cvt_e4m3(float x) {
    __hip_fp8_e4m3 t(x);          // OCP e4m3fn, RNE + satfinite
    return t.__x;
}

// tanh(x) = 1 - 2/(exp(2x)+1)
__device__ __forceinline__ float fast_tanh(float x) {
    float xc = fminf(fmaxf(x, -15.0f), 15.0f);
    float e = __expf(2.0f * xc);
    float r = __builtin_amdgcn_rcpf(e + 1.0f);
    return 1.0f - 2.0f * r;
}

// ---------------- fused prep: zero accumulators + fp32->fp8 all 5 tensors ----------------
__global__ void prep_kernel(const float* __restrict__ A,
                            const float* __restrict__ W1m, const float* __restrict__ W2m,
                            const float* __restrict__ W1v, const float* __restrict__ W2v,
                            unsigned char* __restrict__ A_f8,
                            unsigned char* __restrict__ W1m_f8, unsigned char* __restrict__ W2m_f8,
                            unsigned char* __restrict__ W1v_f8, unsigned char* __restrict__ W2v_f8,
                            float* __restrict__ zbuf, int nzero) {
    const int tid = blockIdx.x * blockDim.x + threadIdx.x;
    if (tid < nzero) zbuf[tid] = 0.0f;
    constexpr int A4 = Bn * Hn / 4;    // 4-elem units
    constexpr int W4 = Hn * Hn / 4;
    const int total = A4 + 4 * W4;
    const int stride = gridDim.x * blockDim.x;
    for (int i = tid; i < total; i += stride) {
        const float* s; unsigned char* d; int j;
        if (i < A4) { s = A; d = A_f8; j = i; }
        else {
            int k = i - A4; int w = k / W4; j = k - w * W4;
            s = (w == 0) ? W1m : (w == 1) ? W2m : (w == 2) ? W1v : W2v;
            d = (w == 0) ? W1m_f8 : (w == 1) ? W2m_f8 : (w == 2) ? W1v_f8 : W2v_f8;
        }
        float4 v = ((const float4*)s)[j];
        unsigned p = (unsigned)cvt_e4m3(v.x)
                   | ((unsigned)cvt_e4m3(v.y) << 8)
                   | ((unsigned)cvt_e4m3(v.z) << 16)
                   | ((unsigned)cvt_e4m3(v.w) << 24);
        ((unsigned*)d)[j] = p;
    }
}

// ---------------- LAYER 1: fp8 paired 128x128 tile, BK=128, swapped operands ----------------
// Computes h1{m,v} = e4m3(tanh(A @ W^T + b)). Operand swap (W as 'a') makes each lane's
// 4 acc regs = 4 consecutive hidden dims of one batch row -> dword fp8 pack.
__launch_bounds__(256, 2)
__global__ void gemm_l1(const unsigned char* __restrict__ A_g,
                        const unsigned char* __restrict__ Wm_g, const unsigned char* __restrict__ Wv_g,
                        const float* __restrict__ bm, const float* __restrict__ bv,
                        unsigned char* __restrict__ outm, unsigned char* __restrict__ outv) {
    __shared__ __align__(16) unsigned char smem[49152];   // As 16K | Wm 16K | Wv 16K
    unsigned char* As  = smem;
    unsigned char* Wms = smem + 16384;
    unsigned char* Wvs = smem + 32768;

    const int t = threadIdx.x;
    const int row0 = blockIdx.x * 128;     // batch
    const int col0 = blockIdx.y * 128;     // hidden
    const int w = t >> 6, lane = t & 63;
    const int wm = w >> 1, wn = w & 1;     // 2x2 waves, 64(batch)x64(hidden) per branch
    const int lr = lane & 15, quad = lane >> 4;
    const int q2 = quad >> 1, q1 = quad & 1;

    // staging: thread t -> row (t>>3), 16B chunk (t&7); XOR source chunk
    const int rst = t >> 3, cst = t & 7;
    const int csrc = cst ^ (rst & 7);

    const unsigned char* pA[4]; const unsigned char* pWm[4]; const unsigned char* pWv[4];
#pragma unroll
    for (int i = 0; i < 4; ++i) {
        pA[i]  = A_g  + (size_t)(row0 + i * 32 + rst) * Hn + csrc * 16;
        pWm[i] = Wm_g + (size_t)(col0 + i * 32 + rst) * Hn + csrc * 16;
        pWv[i] = Wv_g + (size_t)(col0 + i * 32 + rst) * Hn + csrc * 16;
    }

    v4f accm[4][4] = {}, accv[4][4] = {};   // [nt(hidden)][mt(batch)]

    for (int k0 = 0; k0 < Hn; k0 += 128) {
#pragma unroll
        for (int i = 0; i < 4; ++i) {
            __builtin_amdgcn_global_load_lds((AS1 void*)pA[i],  (AS3 void*)&As[i * 4096 + t * 16], 16, 0, 0);
            __builtin_amdgcn_global_load_lds((AS1 void*)pWm[i], (AS3 void*)&Wms[i * 4096 + t * 16], 16, 0, 0);
            __builtin_amdgcn_global_load_lds((AS1 void*)pWv[i], (AS3 void*)&Wvs[i * 4096 + t * 16], 16, 0, 0);
            pA[i] += 128; pWm[i] += 128; pWv[i] += 128;
        }
        __syncthreads();
#pragma unroll
        for (int ks = 0; ks < 4; ++ks) {
            const int cg = ks * 2 + q2;
            long fb[4], fam[4], fav[4];
#pragma unroll
            for (int mt = 0; mt < 4; ++mt) {
                int m = wm * 64 + mt * 16 + lr;
                fb[mt] = *(const long*)&As[m * 128 + ((cg ^ (m & 7)) << 4) + (q1 << 3)];
            }
#pragma unroll
            for (int nt = 0; nt < 4; ++nt) {
                int n = wn * 64 + nt * 16 + lr;
                int off = n * 128 + ((cg ^ (n & 7)) << 4) + (q1 << 3);
                fam[nt] = *(const long*)&Wms[off];
                fav[nt] = *(const long*)&Wvs[off];
            }
#pragma unroll
            for (int nt = 0; nt < 4; ++nt)
#pragma unroll
                for (int mt = 0; mt < 4; ++mt) {
                    accm[nt][mt] = __builtin_amdgcn_mfma_f32_16x16x32_fp8_fp8(fam[nt], fb[mt], accm[nt][mt], 0, 0, 0);
                    accv[nt][mt] = __builtin_amdgcn_mfma_f32_16x16x32_fp8_fp8(fav[nt], fb[mt], accv[nt][mt], 0, 0, 0);
                }
        }
        __syncthreads();
    }

    // epilogue: D row = quad*4+reg = hidden, D col = lane&15 = batch.
    // pack 4 hidden-consecutive fp8 -> dword, LDS transpose (pad 36 dw), coalesced 16B stores.
    unsigned* sm32 = (unsigned*)smem;
#pragma unroll
    for (int br = 0; br < 2; ++br) {
        const float* bias = br ? bv : bm;
        unsigned char* out = br ? outv : outm;
#pragma unroll
        for (int nt = 0; nt < 4; ++nt) {
            float4 bb = *(const float4*)&bias[col0 + wn * 64 + nt * 16 + quad * 4];
#pragma unroll
            for (int mt = 0; mt < 4; ++mt) {
                const int row_l = wm * 64 + mt * 16 + lr;   // batch row in tile
                v4f a = br ? accv[nt][mt] : accm[nt][mt];
                unsigned p = (unsigned)cvt_e4m3(fast_tanh(a[0] + bb.x))
                           | ((unsigned)cvt_e4m3(fast_tanh(a[1] + bb.y)) << 8)
                           | ((unsigned)cvt_e4m3(fast_tanh(a[2] + bb.z)) << 16)
                           | ((unsigned)cvt_e4m3(fast_tanh(a[3] + bb.w)) << 24);
                sm32[row_l * 36 + wn * 16 + nt * 4 + quad] = p;
            }
        }
        __syncthreads();
#pragma unroll
        for (int i = 0; i < 4; ++i) {
            const int idx = i * 256 + t;
            const int row = idx >> 3, seg = idx & 7;
            uint4 d = *(const uint4*)&sm32[row * 36 + seg * 4];
            *(uint4*)&out[(size_t)(row0 + row) * Hn + col0 + seg * 16] = d;
        }
        __syncthreads();
    }
}

// ---------------- LAYER 2: fp8 branch-paired 128x128, BK=128, CLUB epilogue + finalize ----------------
__launch_bounds__(256, 2)
__global__ void gemm_l2(const unsigned char* __restrict__ Am_g, const unsigned char* __restrict__ Av_g,
                        const unsigned char* __restrict__ Wm_g, const unsigned char* __restrict__ Wv_g,
                        const float* __restrict__ bm, const float* __restrict__ bv,
                        const float* __restrict__ mb,
                        float* __restrict__ cs, float* __restrict__ cs2,
                        float* __restrict__ siv, float* __restrict__ sivmu,
                        float* __restrict__ accum, float* __restrict__ outp) {
    __shared__ __align__(16) unsigned char smem[65536];
    unsigned char* Ams = smem;
    unsigned char* Avs = smem + 16384;
    unsigned char* Wms = smem + 32768;
    unsigned char* Wvs = smem + 49152;

    const int t = threadIdx.x;
    const int row0 = blockIdx.x * 128;
    const int col0 = blockIdx.y * 128;
    const int w = t >> 6, lane = t & 63;
    const int wm = w >> 1, wn = w & 1;
    const int lr = lane & 15, quad = lane >> 4;
    const int q2 = quad >> 1, q1 = quad & 1;

    const int rst = t >> 3, cst = t & 7;
    const int csrc = cst ^ (rst & 7);

    const unsigned char* pAm[4]; const unsigned char* pAv[4];
    const unsigned char* pWm[4]; const unsigned char* pWv[4];
#pragma unroll
    for (int i = 0; i < 4; ++i) {
        pAm[i] = Am_g + (size_t)(row0 + i * 32 + rst) * Hn + csrc * 16;
        pAv[i] = Av_g + (size_t)(row0 + i * 32 + rst) * Hn + csrc * 16;
        pWm[i] = Wm_g + (size_t)(col0 + i * 32 + rst) * Hn + csrc * 16;
        pWv[i] = Wv_g + (size_t)(col0 + i * 32 + rst) * Hn + csrc * 16;
    }

    v4f accm[4][4] = {}, accv[4][4] = {};   // [mt(batch)][nt(hidden)] standard orientation

    for (int k0 = 0; k0 < Hn; k0 += 128) {
#pragma unroll
        for (int i = 0; i < 4; ++i) {
            __builtin_amdgcn_global_load_lds((AS1 void*)pAm[i], (AS3 void*)&Ams[i * 4096 + t * 16], 16, 0, 0);
            __builtin_amdgcn_global_load_lds((AS1 void*)pAv[i], (AS3 void*)&Avs[i * 4096 + t * 16], 16, 0, 0);
            __builtin_amdgcn_global_load_lds((AS1 void*)pWm[i], (AS3 void*)&Wms[i * 4096 + t * 16], 16, 0, 0);
            __builtin_amdgcn_global_load_lds((AS1 void*)pWv[i], (AS3 void*)&Wvs[i * 4096 + t * 16], 16, 0, 0);
            pAm[i] += 128; pAv[i] += 128; pWm[i] += 128; pWv[i] += 128;
        }
        __syncthreads();
#pragma unroll
        for (int ks = 0; ks < 4; ++ks) {
            const int cg = ks * 2 + q2;
            long fam[4], fav[4], fwm[4], fwv[4];
#pragma unroll
            for (int mt = 0; mt < 4; ++mt) {
                int m = wm * 64 + mt * 16 + lr;
                int off = m * 128 + ((cg ^ (m & 7)) << 4) + (q1 << 3);
                fam[mt] = *(const long*)&Ams[off];
                fav[mt] = *(const long*)&Avs[off];
            }
#pragma unroll
            for (int nt = 0; nt < 4; ++nt) {
                int n = wn * 64 + nt * 16 + lr;
                int off = n * 128 + ((cg ^ (n & 7)) << 4) + (q1 << 3);
                fwm[nt] = *(const long*)&Wms[off];
                fwv[nt] = *(const long*)&Wvs[off];
            }
#pragma unroll
            for (int mt = 0; mt < 4; ++mt)
#pragma unroll
                for (int nt = 0; nt < 4; ++nt) {
                    accm[mt][nt] = __builtin_amdgcn_mfma_f32_16x16x32_fp8_fp8(fam[mt], fwm[nt], accm[mt][nt], 0, 0, 0);
                    accv[mt][nt] = __builtin_amdgcn_mfma_f32_16x16x32_fp8_fp8(fav[mt], fwv[nt], accv[mt][nt], 0, 0, 0);
                }
        }
        __syncthreads();
    }

    // ---------------- CLUB epilogue: col=lane&15 (hidden), row=quad*4+r (batch) ----------------
    float pos = 0.f, q = 0.f;   // pos = sum iv*(mu-mb)^2 ; q = sum iv*mu^2
#pragma unroll
    for (int nt = 0; nt < 4; ++nt) {
        const int col = col0 + wn * 64 + nt * 16 + lr;
        const float bmc = bm[col], bvc = bv[col];
        float c1 = 0.f, c2 = 0.f, c3 = 0.f, c4 = 0.f;
#pragma unroll
        for (int mt = 0; mt < 4; ++mt) {
#pragma unroll
            for (int r = 0; r < 4; ++r) {
                const int row = row0 + wm * 64 + mt * 16 + quad * 4 + r;
                float mu = accm[mt][nt][r] + bmc;
                float tv = fast_tanh(accv[mt][nt][r] + bvc);
                float iv = __expf(-tv);
                float mbv = mb[(size_t)row * Hn + col];
                float d = mu - mbv;
                pos += iv * d * d;
                q   += iv * mu * mu;
                c1 += mu; c2 += mu * mu; c3 += iv; c4 += iv * mu;
            }
        }
        c1 += __shfl_xor(c1, 16); c1 += __shfl_xor(c1, 32);
        c2 += __shfl_xor(c2, 16); c2 += __shfl_xor(c2, 32);
        c3 += __shfl_xor(c3, 16); c3 += __shfl_xor(c3, 32);
        c4 += __shfl_xor(c4, 16); c4 += __shfl_xor(c4, 32);
        if (quad == 0) {
            atomicAdd(&cs[col], c1);
            atomicAdd(&cs2[col], c2);
            atomicAdd(&siv[col], c3);
            atomicAdd(&sivmu[col], c4);
        }
    }
    for (int off = 32; off > 0; off >>= 1) {
        pos += __shfl_down(pos, off);
        q   += __shfl_down(q, off);
    }
    __shared__ float redP[4], redQ[4];
    if (lane == 0) { redP[w] = pos; redQ[w] = q; }
    __syncthreads();
    __shared__ int is_last;
    if (t == 0) {
        atomicAdd(&accum[0], redP[0] + redP[1] + redP[2] + redP[3]);
        atomicAdd(&accum[1], redQ[0] + redQ[1] + redQ[2] + redQ[3]);
        __threadfence();
        unsigned old = atomicAdd((unsigned int*)&accum[3], 1u);
        is_last = (old == gridDim.x * gridDim.y - 1) ? 1 : 0;
    }
    __syncthreads();
    if (is_last) {
        float term = 0.f;
        for (int h = t; h < Hn; h += 256) {
            float v1 = atomicAdd(&cs[h], 0.0f);
            float v2 = atomicAdd(&cs2[h], 0.0f);
            float v3 = atomicAdd(&siv[h], 0.0f);
            float v4 = atomicAdd(&sivmu[h], 0.0f);
            term += v3 * v2 - 2.0f * v4 * v1;
        }
        for (int off = 32; off > 0; off >>= 1) term += __shfl_down(term, off);
        __shared__ float redT[4];
        if (lane == 0) redT[w] = term;
        __syncthreads();
        if (t == 0) {
            float T = redT[0] + redT[1] + redT[2] + redT[3];
            float P = atomicAdd(&accum[0], 0.0f);
            float Q = atomicAdd(&accum[1], 0.0f);
            float pos_sum = -0.5f * P;
            float neg_sum = -0.5f * (T * invB + Q);
            outp[0] = pos_sum * invB;
            outp[1] = (pos_sum - neg_sum) * invB;
        }
    }
}

extern "C" void kernel_launch(void* const* d_in, const int* in_sizes, int n_in,
                              void* d_out, int out_size, void* d_ws, size_t ws_size,
                              hipStream_t stream) {
    const float* modal_a = (const float*)d_in[0];
    const float* modal_b = (const float*)d_in[1];
    const float* W1m = (const float*)d_in[2];
    const float* b1m = (const float*)d_in[3];
    const float* W2m = (const float*)d_in[4];
    const float* b2m = (const float*)d_in[5];
    const float* W1v = (const float*)d_in[6];
    const float* b1v = (const float*)d_in[7];
    const float* W2v = (const float*)d_in[8];
    const float* b2v = (const float*)d_in[9];
    float* out = (float*)d_out;

    char* ws = (char*)d_ws;
    constexpr size_t szA8 = (size_t)Bn * Hn;       // fp8 [B,H] = 6.29 MB
    constexpr size_t szW8 = (size_t)Hn * Hn;       // fp8 [H,H] = 0.59 MB
    unsigned char* A_f8   = (unsigned char*)(ws);
    unsigned char* h1m_f8 = (unsigned char*)(ws + szA8);
    unsigned char* h1v_f8 = (unsigned char*)(ws + 2 * szA8);
    unsigned char* W1m_f8 = (unsigned char*)(ws + 3 * szA8);
    unsigned char* W2m_f8 = (unsigned char*)(ws + 3 * szA8 + szW8);
    unsigned char* W1v_f8 = (unsigned char*)(ws + 3 * szA8 + 2 * szW8);
    unsigned char* W2v_f8 = (unsigned char*)(ws + 3 * szA8 + 3 * szW8);
    float* cs     = (float*)(ws + 3 * szA8 + 4 * szW8);
    float* cs2    = cs + Hn;
    float* siv    = cs + 2 * Hn;
    float* sivmu  = cs + 3 * Hn;
    float* accum  = cs + 4 * Hn;   // [0]=P [1]=Q [2]=pad [3]=ticket

    // 1. fused zero + fp32->fp8 convert (A + 4 W)
    prep_kernel<<<1280, 256, 0, stream>>>(modal_a, W1m, W2m, W1v, W2v,
                                          A_f8, W1m_f8, W2m_f8, W1v_f8, W2v_f8,
                                          cs, 4 * Hn + 8);

    // 2. layer-1 fp8 paired GEMM -> h1{m,v} fp8
    gemm_l1<<<dim3(Bn / 128, Hn / 128), 256, 0, stream>>>(
        A_f8, W1m_f8, W1v_f8, b1m, b1v, h1m_f8, h1v_f8);

    // 3. layer-2 fp8 paired GEMM + CLUB epilogue + in-kernel finalize
    gemm_l2<<<dim3(Bn / 128, Hn / 128), 256, 0, stream>>>(
        h1m_f8, h1v_f8, W2m_f8, W2v_f8, b2m, b2v, modal_b,
        cs, cs2, siv, sivmu, accum, out);
}